// Round 19
// baseline (98.959 us; speedup 1.0000x reference)
//
#include <hip/hip_runtime.h>

typedef unsigned short u16;
typedef unsigned int u32;
typedef __attribute__((ext_vector_type(8))) short short8;   // 8 bf16 (MFMA A/B frag)
typedef __attribute__((ext_vector_type(4))) float f32x4;    // MFMA C/D frag
typedef __attribute__((ext_vector_type(4))) float fvec4;
typedef __attribute__((ext_vector_type(4))) u16 u16x4;

typedef __attribute__((address_space(1))) void gvoid;
typedef __attribute__((address_space(3))) void lvoid;

__device__ __forceinline__ u16 f2bf(float f) {
  u32 u = __float_as_uint(f);
  u += 0x7FFFu + ((u >> 16) & 1u);   // RTNE
  return (u16)(u >> 16);
}

// async global->LDS DMA, 16B/lane: LDS dest = uniform base + lane*16, global src per-lane.
__device__ __forceinline__ void gl16(const u16* g, u16* d) {
  __builtin_amdgcn_global_load_lds((gvoid*)g, (lvoid*)d, 16, 0, 0);
}

// wave-local LDS fence: drains this wave's ds ops only (lgkmcnt), does NOT touch vmcnt.
__device__ __forceinline__ void wave_lds_fence() {
  asm volatile("s_waitcnt lgkmcnt(0)" ::: "memory");
  __builtin_amdgcn_sched_barrier(0);
}

// memory row index of token (Bg,h,w); rows of x are 256 elems.
__device__ __forceinline__ int m_of(int Bg, int h, int w) {
  return ((Bg >> 2) << 14) | ((h & 3) << 12) | ((((Bg & 3) << 1) | (h >> 5)) << 9) |
         (((h >> 2) & 7) << 6) | w;
}

__device__ __forceinline__ f32x4 mfma16(short8 a, short8 b, f32x4 c) {
  return __builtin_amdgcn_mfma_f32_16x16x32_bf16(a, b, c, 0, 0, 0);
}

// qkvB blocked layout: element (channel c, token m) lives at (c>>2)*262144 + m*4 + (c&3).
__device__ __forceinline__ short8 ld8(const u16* __restrict__ qb, int c4, int m) {
  union { u16x4 h[2]; short8 v; } u;
  u.h[0] = *(const u16x4*)(qb + (size_t)c4 * 262144 + (size_t)m * 4);
  u.h[1] = *(const u16x4*)(qb + (size_t)(c4 + 1) * 262144 + (size_t)m * 4);
  return u.v;
}

// ---------------- prep: pack W into DMA-ready swizzled order + bias matrices --------------
__global__ void k_prep(const float* __restrict__ qkv_w, const float* __restrict__ t0,
                       const float* __restrict__ t1, u16* __restrict__ wbp,
                       float* __restrict__ bias4, float* __restrict__ bias8) {
  int tid = blockIdx.x * 256 + threadIdx.x;
  int stride = gridDim.x * 256;
  for (int i = tid; i < 196608; i += stride) {
    int nhc = i / 12288;              // (nh*8 + chunk) in [0,16)
    int rem = i - nhc * 12288;
    int p = rem >> 3, e = rem & 7;
    int cu = p >> 2;
    int su = (p & 3) ^ ((cu >> 1) & 3);
    int col = (nhc >> 3) * 384 + cu;
    int k = (nhc & 7) * 32 + su * 8 + e;
    wbp[i] = f2bf(qkv_w[col * 256 + k]);
  }
  for (int i = tid; i < 4 * 64 * 64; i += stride) {
    int g = i >> 12, n = (i >> 6) & 63, m = i & 63;
    int di = (n >> 3) - (m >> 3) + 7, dj = (n & 7) - (m & 7) + 7;
    bias8[i] = t1[(di * 15 + dj) * 4 + g];
  }
  for (int i = tid; i < 4 * 16 * 16; i += stride) {
    int g = i >> 8, n = (i >> 4) & 15, m = i & 15;
    int di = (n >> 2) - (m >> 2) + 3, dj = (n & 3) - (m & 3) + 3;
    bias4[i] = t0[(di * 7 + dj) * 4 + g];
  }
}

// ---------------- QKV GEMM: [65536 x 256] x [256 x 768] -> qkvB blocked layout ------------
// ROUND-18 PROVEN (~28us): grid 2048, pairing swizzle; FULL As 64x256 (32KB, slot-swizzled,
// no K-half restage, single prologue barrier); B via global_load_lds from pre-swizzled wbp,
// per-wave dbuf slabs, 2-deep counted vmcnt(3); LDS exactly 80KB -> 2 blocks/CU.
__global__ __launch_bounds__(512, 4) void k_gemm(const float* __restrict__ x,
                                                 const u16* __restrict__ wbp,
                                                 const float* __restrict__ qkv_b,
                                                 u16* __restrict__ qkvB) {
  __shared__ __align__(16) u16 As[64 * 256];       // 32768 B, XOR slot-swizzled, full K
  __shared__ __align__(16) u16 Bs[2 * 8 * 1536];   // 49152 B: [buf][wave][48 cols x 32 k]
  const int t = threadIdx.x;
  const int wid = t >> 6, l = t & 63;
  const int lr = l & 15, lk4 = l >> 4;
  const int mt = ((blockIdx.x >> 4) << 3) | (blockIdx.x & 7);  // pairing swizzle
  const int nh = (blockIdx.x >> 3) & 1;
  const size_t xbase = (size_t)mt * 64 * 256;
  const int colbase = nh * 384;            // this block's first output col

  // B DMA geometry: src has per-lane l*8; dest base is wave-uniform (HW adds lane*16B)
  const u16* wsrc = wbp + (size_t)(nh * 8) * 12288 + (wid * 192 + l) * 8;
  u16* bdst = &Bs[wid * 1536];

  // ---- (1) bias pre-load: OLDEST VMEM, pinned before any DMA ----
  fvec4 bb[3];
#pragma unroll
  for (int jt = 0; jt < 3; ++jt)
    bb[jt] = *(const fvec4*)(qkv_b + colbase + wid * 48 + jt * 16 + lk4 * 4);
  asm volatile("" ::: "memory");           // bias loads stay above everything below

  // ---- (2) DMA chunk0 -> buf0, chunk1 -> buf1 ----
#pragma unroll
  for (int j = 0; j < 3; ++j) gl16(wsrc + j * 512, bdst + j * 512);
#pragma unroll
  for (int j = 0; j < 3; ++j) gl16(wsrc + 12288 + j * 512, bdst + 12288 + j * 512);
  asm volatile("" ::: "memory");           // pin DMA issue order before x loads

  // ---- (3) stage FULL As: thread covers col (t&63)*4, rows wid + it*8 ----
  {
    const int cc = (l & 63) * 4;           // u16 col, multiple of 4
    const int slot = cc >> 3, half = cc & 7;
    const float* xp = x + xbase + (size_t)wid * 256 + cc;
#pragma unroll
    for (int it = 0; it < 8; ++it) {
      fvec4 v = *(const fvec4*)(xp + it * 8 * 256);
      int r = wid + it * 8;
      u16x4 u;
      u[0] = f2bf(v[0]); u[1] = f2bf(v[1]); u[2] = f2bf(v[2]); u[3] = f2bf(v[3]);
      *(u16x4*)&As[r * 256 + ((slot ^ (r & 7)) << 3) + half] = u;
    }
  }
  asm volatile("s_waitcnt lgkmcnt(0)" ::: "memory");
  __builtin_amdgcn_s_barrier();            // As visible — the ONLY barrier in this kernel

  f32x4 acc[3][4];
  const f32x4 z = {0.f, 0.f, 0.f, 0.f};
#pragma unroll
  for (int jt = 0; jt < 3; ++jt)
#pragma unroll
    for (int rt = 0; rt < 4; ++rt) acc[jt][rt] = z;

  const int bswz = (lr >> 1) & 3;          // B-read slot swizzle
#pragma unroll
  for (int ci = 0; ci < 8; ++ci) {
    const int buf = ci & 1;
    // counted wait: chunk ci is the 2nd-newest DMA group in FIFO -> vmcnt(3) retires it;
    // chunk ci+1 (newest, 3 ops) stays in flight. Last iter: full drain.
    if (ci == 7) asm volatile("s_waitcnt vmcnt(0)" ::: "memory");
    else         asm volatile("s_waitcnt vmcnt(3)" ::: "memory");
    __builtin_amdgcn_sched_barrier(0);
    // reads (LDS only)
    short8 a[4], b[3];
    const int kslot = ci * 4 + lk4;        // 0..31 within full 256-K row
#pragma unroll
    for (int rt = 0; rt < 4; ++rt) {
      int row = rt * 16 + lr;
      a[rt] = *(const short8*)&As[row * 256 + ((kslot ^ (row & 7)) << 3)];
    }
#pragma unroll
    for (int jt = 0; jt < 3; ++jt)
      b[jt] = *(const short8*)&Bs[buf * 12288 + wid * 1536 +
                                  (jt * 16 + lr) * 32 + ((lk4 ^ bswz) * 8)];
    // drain reads into regs -> WAR-safe to DMA into this buffer below
    asm volatile("s_waitcnt lgkmcnt(0)" ::: "memory");
    __builtin_amdgcn_sched_barrier(0);
    if (ci < 6) {                          // issue chunk ci+2 into buf(ci&1)
      const u16* s = wsrc + (size_t)(ci + 2) * 12288;
      u16* d = bdst + buf * 12288;
#pragma unroll
      for (int j = 0; j < 3; ++j) gl16(s + j * 512, d + j * 512);
    }
    __builtin_amdgcn_sched_barrier(0);
#pragma unroll
    for (int jt = 0; jt < 3; ++jt)
#pragma unroll
      for (int rt = 0; rt < 4; ++rt)
        acc[jt][rt] = mfma16(b[jt], a[rt], acc[jt][rt]);  // reg-dim = col
  }

  // ---- epilogue: + pre-loaded bias, blocked layout -> per-lane u16x4, coalesced ----
  const int rows0 = mt * 64;
#pragma unroll
  for (int jt = 0; jt < 3; ++jt) {
    int col0 = colbase + wid * 48 + jt * 16 + lk4 * 4;
    int c40 = col0 >> 2;
#pragma unroll
    for (int rt = 0; rt < 4; ++rt) {
      int row = rows0 + rt * 16 + lr;
      u16x4 u;
#pragma unroll
      for (int r = 0; r < 4; ++r) u[r] = f2bf(acc[jt][rt][r] + bb[jt][r]);
      *(u16x4*)&qkvB[(size_t)c40 * 262144 + (size_t)row * 4] = u;
    }
  }
}

// ---------------- attention ws=8 (group 1, channels 128..255) ----------------
// 1-wave blocks (grid 4096 = window x head), XCD-chunked swizzle; no barriers at all.
__global__ __launch_bounds__(64) void k_attn8(const u16* __restrict__ qkvB,
                                              const float* __restrict__ bias8,
                                              float* __restrict__ out) {
  __shared__ __align__(16) u16 vtg[32 * 72];  // V^T [e][m] (pad 8)
  __shared__ __align__(16) u16 plg[64 * 72];  // P [n][m]; reused as O f32 [64][33]
  const int lid = blockIdx.x;
  const int logical = (lid & 7) * 512 + (lid >> 3);  // bijective: 4096 = 8*512
  const int g = logical & 3;
  const int wj = (logical >> 2) & 7, wi = (logical >> 5) & 7, Bg = logical >> 8;
  const int h0 = wi * 8, w0 = wj * 8;
  const int l = threadIdx.x;
  const int lr = l & 15, lk4 = l >> 4;

  const int c4q = 32 + g * 8 + lk4 * 2;   // q chans 128+g*32+lk4*8
  const int c4k = 96 + g * 8 + lk4 * 2;   // k chans 384+g*32+lk4*8
  short8 aq[4], bk[4];
#pragma unroll
  for (int tn = 0; tn < 4; ++tn) {
    int n = tn * 16 + lr;
    int m = m_of(Bg, h0 + (n >> 3), w0 + (n & 7));
    aq[tn] = ld8(qkvB, c4q, m);
    bk[tn] = ld8(qkvB, c4k, m);
  }
  // stage V^T: lane l owns token m=l; v chans 640+g*32 .. +31 (8 c4-groups)
  {
    int m = m_of(Bg, h0 + (l >> 3), w0 + (l & 7));
#pragma unroll
    for (int j2 = 0; j2 < 8; ++j2) {
      u16x4 p = *(const u16x4*)(qkvB + (size_t)(160 + g * 8 + j2) * 262144 + (size_t)m * 4);
#pragma unroll
      for (int r = 0; r < 4; ++r) vtg[(j2 * 4 + r) * 72 + l] = p[r];
    }
  }
  // S = q k^T  (16 MFMAs)
  f32x4 z = {0.f, 0.f, 0.f, 0.f};
  f32x4 s[4][4];
#pragma unroll
  for (int tn = 0; tn < 4; ++tn)
#pragma unroll
    for (int tm = 0; tm < 4; ++tm) s[tn][tm] = mfma16(aq[tn], bk[tm], z);

  const float scale = 0.17677669529663687f;  // 1/sqrt(32)
#pragma unroll
  for (int tn = 0; tn < 4; ++tn)
#pragma unroll
    for (int tm = 0; tm < 4; ++tm)
#pragma unroll
      for (int r = 0; r < 4; ++r) {
        int n = tn * 16 + lk4 * 4 + r, m = tm * 16 + lr;
        s[tn][tm][r] = s[tn][tm][r] * scale + bias8[(g * 64 + n) * 64 + m];
      }
  // softmax over m (row n lives in 16 lanes sharing l>>4)
  float invden[4][4];
#pragma unroll
  for (int tn = 0; tn < 4; ++tn)
#pragma unroll
    for (int r = 0; r < 4; ++r) {
      float mx = fmaxf(fmaxf(s[tn][0][r], s[tn][1][r]), fmaxf(s[tn][2][r], s[tn][3][r]));
#pragma unroll
      for (int d = 1; d < 16; d <<= 1) mx = fmaxf(mx, __shfl_xor(mx, d));
      float sum = 0.f;
#pragma unroll
      for (int tm = 0; tm < 4; ++tm) {
        float p = __expf(s[tn][tm][r] - mx);
        s[tn][tm][r] = p;
        sum += p;
      }
#pragma unroll
      for (int d = 1; d < 16; d <<= 1) sum += __shfl_xor(sum, d);
      invden[tn][r] = 1.f / sum;
    }
  // P -> LDS (bf16)
#pragma unroll
  for (int tn = 0; tn < 4; ++tn)
#pragma unroll
    for (int tm = 0; tm < 4; ++tm)
#pragma unroll
      for (int r = 0; r < 4; ++r)
        plg[(tn * 16 + lk4 * 4 + r) * 72 + tm * 16 + lr] = f2bf(s[tn][tm][r]);
  wave_lds_fence();
  // O = P V  (16 MFMAs)
  f32x4 o[4][2];
#pragma unroll
  for (int tn = 0; tn < 4; ++tn) { o[tn][0] = z; o[tn][1] = z; }
#pragma unroll
  for (int kc = 0; kc < 2; ++kc) {
    short8 pa[4], vb[2];
#pragma unroll
    for (int tn = 0; tn < 4; ++tn)
      pa[tn] = *(const short8*)&plg[(tn * 16 + lr) * 72 + kc * 32 + lk4 * 8];
#pragma unroll
    for (int te = 0; te < 2; ++te)
      vb[te] = *(const short8*)&vtg[(te * 16 + lr) * 72 + kc * 32 + lk4 * 8];
#pragma unroll
    for (int tn = 0; tn < 4; ++tn)
#pragma unroll
      for (int te = 0; te < 2; ++te) o[tn][te] = mfma16(pa[tn], vb[te], o[tn][te]);
  }
  wave_lds_fence();
  // scale by 1/denom, transpose O through LDS (overlay on plg)
  float* ol = (float*)plg;  // [64][33]
#pragma unroll
  for (int tn = 0; tn < 4; ++tn)
#pragma unroll
    for (int te = 0; te < 2; ++te)
#pragma unroll
      for (int r = 0; r < 4; ++r) {
        int n = tn * 16 + lk4 * 4 + r;
        ol[n * 33 + te * 16 + lr] = o[tn][te][r] * invden[tn][r];
      }
  wave_lds_fence();
  // store: lane = token, loop e -> 32B-chunk runs along w (row-mates share XCD)
  {
    int h = h0 + (l >> 3), w = w0 + (l & 7);
    size_t base = ((size_t)(Bg >> 2)) * 4194304 + (size_t)(((Bg & 3) * 2 + (h >> 5))) * 131072 +
                  (size_t)(((h >> 2) & 7)) * 16384 + (size_t)((h & 3) * 64 + w);
#pragma unroll
    for (int e = 0; e < 32; ++e) {
      int c = 128 + g * 32 + e;
      size_t idx = base + (size_t)(c >> 6) * 1048576 + (size_t)((c >> 3) & 7) * 2048 +
                   (size_t)(c & 7) * 256;
      out[idx] = ol[l * 33 + e];
    }
  }
}

// ---------------- attention ws=4 (group 0, channels 0..127) ----------------
// 1-wave blocks (grid 16384 = window x head), no g-loop, no barriers; XCD-chunked swizzle.
__global__ __launch_bounds__(64) void k_attn4(const u16* __restrict__ qkvB,
                                              const float* __restrict__ bias4,
                                              float* __restrict__ out) {
  __shared__ __align__(16) u16 vtw[32 * 40];   // V^T [e][m0..32] (m 16..31 zero)
  __shared__ __align__(16) u16 plw[16 * 40];   // P [n][m0..32] (m 16..31 zero)
  __shared__ __align__(16) float olw[16 * 33]; // O
  const int lid = blockIdx.x;
  const int logical = (lid & 7) * 2048 + (lid >> 3);  // bijective: 16384 = 8*2048
  const int g = logical & 3;
  const int wid2 = logical >> 2;               // window id in [0,4096)
  const int Bg = wid2 >> 8, wi = (wid2 >> 4) & 15, wj = wid2 & 15;
  const int h0 = wi * 4, w0 = wj * 4;
  const int l = threadIdx.x;
  const int lr = l & 15, lk4 = l >> 4;
  const f32x4 z = {0.f, 0.f, 0.f, 0.f};
  const short8 z8 = {0, 0, 0, 0, 0, 0, 0, 0};
  const float scale = 0.17677669529663687f;

  // zero the K-padding (cols 16..31) of P and V^T
  {
    u16x4 z4 = {0, 0, 0, 0};
    *(u16x4*)&plw[(l & 15) * 40 + 16 + (l >> 4) * 4] = z4;
    *(short8*)&vtw[(l >> 1) * 40 + 16 + (l & 1) * 8] = z8;
  }
  // per-lane token index
  const int mq = m_of(Bg, h0 + (lr >> 2), w0 + (lr & 3));

  short8 aq = ld8(qkvB, g * 8 + lk4 * 2, mq);          // q chans g*32+lk4*8
  short8 bk = ld8(qkvB, 64 + g * 8 + lk4 * 2, mq);     // k chans 256+g*32+lk4*8
  // stage V^T: lane = (token lr) x (e-chunk lk4)
  {
    short8 v = ld8(qkvB, 128 + g * 8 + lk4 * 2, mq);   // v chans 512+g*32+lk4*8
#pragma unroll
    for (int j = 0; j < 8; ++j) vtw[(lk4 * 8 + j) * 40 + lr] = (u16)v[j];
  }
  // S (1 MFMA), C rows n = lk4*4+r, cols m = lr
  f32x4 s = mfma16(aq, bk, z);
#pragma unroll
  for (int r = 0; r < 4; ++r) {
    int n = lk4 * 4 + r;
    s[r] = s[r] * scale + bias4[(g * 16 + n) * 16 + lr];
  }
  float invden[4];
#pragma unroll
  for (int r = 0; r < 4; ++r) {
    float mx = s[r];
#pragma unroll
    for (int d = 1; d < 16; d <<= 1) mx = fmaxf(mx, __shfl_xor(mx, d));
    float p = __expf(s[r] - mx);
    s[r] = p;
    float sum = p;
#pragma unroll
    for (int d = 1; d < 16; d <<= 1) sum += __shfl_xor(sum, d);
    invden[r] = 1.f / sum;
  }
  // P -> LDS
#pragma unroll
  for (int r = 0; r < 4; ++r) plw[(lk4 * 4 + r) * 40 + lr] = f2bf(s[r]);
  wave_lds_fence();
  // O = P V : 2 MFMAs (te halves), K zero-padded to 32
  f32x4 o[2];
#pragma unroll
  for (int te = 0; te < 2; ++te) {
    short8 pa = *(const short8*)&plw[lr * 40 + lk4 * 8];
    short8 vb = *(const short8*)&vtw[(te * 16 + lr) * 40 + lk4 * 8];
    o[te] = mfma16(pa, vb, z);
  }
#pragma unroll
  for (int te = 0; te < 2; ++te)
#pragma unroll
    for (int r = 0; r < 4; ++r) {
      int n = lk4 * 4 + r;
      olw[n * 33 + te * 16 + lr] = o[te][r] * invden[r];
    }
  wave_lds_fence();
  // store: lane = (token lr) x (e-chunk lk4)
  {
    int h = h0 + (lr >> 2), w = w0 + (lr & 3);
    size_t base = ((size_t)(Bg >> 2)) * 4194304 +
                  (size_t)(((Bg & 3) * 2 + (h >> 5))) * 131072 +
                  (size_t)(((h >> 2) & 7)) * 16384 + (size_t)((h & 3) * 64 + w);
#pragma unroll
    for (int ee = 0; ee < 8; ++ee) {
      int e = lk4 * 8 + ee;
      int c = g * 32 + e;
      size_t idx = base + (size_t)(c >> 6) * 1048576 + (size_t)((c >> 3) & 7) * 2048 +
                   (size_t)(c & 7) * 256;
      out[idx] = olw[lr * 33 + e];
    }
  }
}

extern "C" void kernel_launch(void* const* d_in, const int* in_sizes, int n_in,
                              void* d_out, int out_size, void* d_ws, size_t ws_size,
                              hipStream_t stream) {
  const float* x = (const float*)d_in[0];
  const float* qkv_w = (const float*)d_in[1];
  const float* qkv_b = (const float*)d_in[2];
  const float* t0 = (const float*)d_in[3];
  const float* t1 = (const float*)d_in[4];
  float* out = (float*)d_out;
  char* ws = (char*)d_ws;

  u16* qkvB = (u16*)ws;                         // 192*65536*4 u16  = 100663296 B
  u16* wbp = (u16*)(ws + 100663296);            // 196608 u16       = 393216 B
  float* bias8 = (float*)(ws + 101056512);      // 4*64*64*4        = 65536 B
  float* bias4 = (float*)(ws + 101122048);      // 4*16*16*4        = 4096 B

  k_prep<<<256, 256, 0, stream>>>(qkv_w, t0, t1, wbp, bias4, bias8);
  k_gemm<<<2048, 512, 0, stream>>>(x, wbp, qkv_b, qkvB);
  k_attn8<<<4096, 64, 0, stream>>>(qkvB, bias8, out);
  k_attn4<<<16384, 64, 0, stream>>>(qkvB, bias4, out);
}

// Round 20
// 88.744 us; speedup vs baseline: 1.1151x; 1.1151x over previous
//
#include <hip/hip_runtime.h>

typedef unsigned short u16;
typedef unsigned int u32;
typedef __attribute__((ext_vector_type(8))) short short8;   // 8 bf16 (MFMA A/B frag)
typedef __attribute__((ext_vector_type(4))) float f32x4;    // MFMA C/D frag
typedef __attribute__((ext_vector_type(4))) float fvec4;
typedef __attribute__((ext_vector_type(4))) u16 u16x4;

typedef __attribute__((address_space(1))) void gvoid;
typedef __attribute__((address_space(3))) void lvoid;

__device__ __forceinline__ u16 f2bf(float f) {
  u32 u = __float_as_uint(f);
  u += 0x7FFFu + ((u >> 16) & 1u);   // RTNE
  return (u16)(u >> 16);
}

// async global->LDS DMA, 16B/lane: LDS dest = uniform base + lane*16, global src per-lane.
__device__ __forceinline__ void gl16(const u16* g, u16* d) {
  __builtin_amdgcn_global_load_lds((gvoid*)g, (lvoid*)d, 16, 0, 0);
}

// wave-local LDS fence: drains this wave's ds ops only (lgkmcnt), does NOT touch vmcnt.
__device__ __forceinline__ void wave_lds_fence() {
  asm volatile("s_waitcnt lgkmcnt(0)" ::: "memory");
  __builtin_amdgcn_sched_barrier(0);
}

// memory row index of token (Bg,h,w); rows of x are 256 elems.
__device__ __forceinline__ int m_of(int Bg, int h, int w) {
  return ((Bg >> 2) << 14) | ((h & 3) << 12) | ((((Bg & 3) << 1) | (h >> 5)) << 9) |
         (((h >> 2) & 7) << 6) | w;
}

__device__ __forceinline__ f32x4 mfma16(short8 a, short8 b, f32x4 c) {
  return __builtin_amdgcn_mfma_f32_16x16x32_bf16(a, b, c, 0, 0, 0);
}

// qkvB8 layout: element (channel c, token m) at (c>>3)*524288 + m*8 + (c&7).
// ld8: 8 consecutive channels (c8*8 .. c8*8+7) at token m -> ONE 16B load.
__device__ __forceinline__ short8 ld8(const u16* __restrict__ qb, int c8, int m) {
  return *(const short8*)(qb + (size_t)c8 * 524288 + (size_t)m * 8);
}

// ---------------- prep: pack W into DMA-ready swizzled order + bias matrices --------------
__global__ void k_prep(const float* __restrict__ qkv_w, const float* __restrict__ t0,
                       const float* __restrict__ t1, u16* __restrict__ wbp,
                       float* __restrict__ bias4, float* __restrict__ bias8) {
  int tid = blockIdx.x * 256 + threadIdx.x;
  int stride = gridDim.x * 256;
  for (int i = tid; i < 196608; i += stride) {
    int nhc = i / 12288;              // (nh*8 + chunk) in [0,16)
    int rem = i - nhc * 12288;
    int p = rem >> 3, e = rem & 7;
    int cu = p >> 2;
    int su = (p & 3) ^ ((cu >> 1) & 3);
    int col = (nhc >> 3) * 384 + cu;
    int k = (nhc & 7) * 32 + su * 8 + e;
    wbp[i] = f2bf(qkv_w[col * 256 + k]);
  }
  for (int i = tid; i < 4 * 64 * 64; i += stride) {
    int g = i >> 12, n = (i >> 6) & 63, m = i & 63;
    int di = (n >> 3) - (m >> 3) + 7, dj = (n & 7) - (m & 7) + 7;
    bias8[i] = t1[(di * 15 + dj) * 4 + g];
  }
  for (int i = tid; i < 4 * 16 * 16; i += stride) {
    int g = i >> 8, n = (i >> 4) & 15, m = i & 15;
    int di = (n >> 2) - (m >> 2) + 3, dj = (n & 3) - (m & 3) + 3;
    bias4[i] = t0[(di * 7 + dj) * 4 + g];
  }
}

// ---------------- QKV GEMM: [65536 x 256] x [256 x 768] -> qkvB8 blocked layout -----------
// ROUND-18 PROVEN structure: grid 2048, pairing swizzle; FULL As 64x256 (32KB, slot-
// swizzled, single prologue barrier, free-run loop); B via global_load_lds from pre-
// swizzled wbp, per-wave dbuf slabs, 2-deep counted vmcnt(3); LDS exactly 80KB.
// ROUND-20: epilogue writes the 8-channel-plane layout (2 planes x 256B per store instr).
__global__ __launch_bounds__(512, 4) void k_gemm(const float* __restrict__ x,
                                                 const u16* __restrict__ wbp,
                                                 const float* __restrict__ qkv_b,
                                                 u16* __restrict__ qkvB) {
  __shared__ __align__(16) u16 As[64 * 256];       // 32768 B, XOR slot-swizzled, full K
  __shared__ __align__(16) u16 Bs[2 * 8 * 1536];   // 49152 B: [buf][wave][48 cols x 32 k]
  const int t = threadIdx.x;
  const int wid = t >> 6, l = t & 63;
  const int lr = l & 15, lk4 = l >> 4;
  const int mt = ((blockIdx.x >> 4) << 3) | (blockIdx.x & 7);  // pairing swizzle
  const int nh = (blockIdx.x >> 3) & 1;
  const size_t xbase = (size_t)mt * 64 * 256;
  const int colbase = nh * 384;            // this block's first output col

  // B DMA geometry: src has per-lane l*8; dest base is wave-uniform (HW adds lane*16B)
  const u16* wsrc = wbp + (size_t)(nh * 8) * 12288 + (wid * 192 + l) * 8;
  u16* bdst = &Bs[wid * 1536];

  // ---- (1) bias pre-load: OLDEST VMEM, pinned before any DMA ----
  fvec4 bb[3];
#pragma unroll
  for (int jt = 0; jt < 3; ++jt)
    bb[jt] = *(const fvec4*)(qkv_b + colbase + wid * 48 + jt * 16 + lk4 * 4);
  asm volatile("" ::: "memory");           // bias loads stay above everything below

  // ---- (2) DMA chunk0 -> buf0, chunk1 -> buf1 ----
#pragma unroll
  for (int j = 0; j < 3; ++j) gl16(wsrc + j * 512, bdst + j * 512);
#pragma unroll
  for (int j = 0; j < 3; ++j) gl16(wsrc + 12288 + j * 512, bdst + 12288 + j * 512);
  asm volatile("" ::: "memory");           // pin DMA issue order before x loads

  // ---- (3) stage FULL As: thread covers col (t&63)*4, rows wid + it*8 ----
  {
    const int cc = (l & 63) * 4;           // u16 col, multiple of 4
    const int slot = cc >> 3, half = cc & 7;
    const float* xp = x + xbase + (size_t)wid * 256 + cc;
#pragma unroll
    for (int it = 0; it < 8; ++it) {
      fvec4 v = *(const fvec4*)(xp + it * 8 * 256);
      int r = wid + it * 8;
      u16x4 u;
      u[0] = f2bf(v[0]); u[1] = f2bf(v[1]); u[2] = f2bf(v[2]); u[3] = f2bf(v[3]);
      *(u16x4*)&As[r * 256 + ((slot ^ (r & 7)) << 3) + half] = u;
    }
  }
  asm volatile("s_waitcnt lgkmcnt(0)" ::: "memory");
  __builtin_amdgcn_s_barrier();            // As visible — the ONLY barrier in this kernel

  f32x4 acc[3][4];
  const f32x4 z = {0.f, 0.f, 0.f, 0.f};
#pragma unroll
  for (int jt = 0; jt < 3; ++jt)
#pragma unroll
    for (int rt = 0; rt < 4; ++rt) acc[jt][rt] = z;

  const int bswz = (lr >> 1) & 3;          // B-read slot swizzle
#pragma unroll
  for (int ci = 0; ci < 8; ++ci) {
    const int buf = ci & 1;
    // counted wait: chunk ci is the 2nd-newest DMA group in FIFO -> vmcnt(3) retires it;
    // chunk ci+1 (newest, 3 ops) stays in flight. Last iter: full drain.
    if (ci == 7) asm volatile("s_waitcnt vmcnt(0)" ::: "memory");
    else         asm volatile("s_waitcnt vmcnt(3)" ::: "memory");
    __builtin_amdgcn_sched_barrier(0);
    // reads (LDS only)
    short8 a[4], b[3];
    const int kslot = ci * 4 + lk4;        // 0..31 within full 256-K row
#pragma unroll
    for (int rt = 0; rt < 4; ++rt) {
      int row = rt * 16 + lr;
      a[rt] = *(const short8*)&As[row * 256 + ((kslot ^ (row & 7)) << 3)];
    }
#pragma unroll
    for (int jt = 0; jt < 3; ++jt)
      b[jt] = *(const short8*)&Bs[buf * 12288 + wid * 1536 +
                                  (jt * 16 + lr) * 32 + ((lk4 ^ bswz) * 8)];
    // drain reads into regs -> WAR-safe to DMA into this buffer below
    asm volatile("s_waitcnt lgkmcnt(0)" ::: "memory");
    __builtin_amdgcn_sched_barrier(0);
    if (ci < 6) {                          // issue chunk ci+2 into buf(ci&1)
      const u16* s = wsrc + (size_t)(ci + 2) * 12288;
      u16* d = bdst + buf * 12288;
#pragma unroll
      for (int j = 0; j < 3; ++j) gl16(s + j * 512, d + j * 512);
    }
    __builtin_amdgcn_sched_barrier(0);
#pragma unroll
    for (int jt = 0; jt < 3; ++jt)
#pragma unroll
      for (int rt = 0; rt < 4; ++rt)
        acc[jt][rt] = mfma16(b[jt], a[rt], acc[jt][rt]);  // reg-dim = col
  }

  // ---- epilogue: + bias, 8-chan-plane layout: store instr fills 2 planes x 256B ----
  const int rows0 = mt * 64;
#pragma unroll
  for (int jt = 0; jt < 3; ++jt) {
    int col0 = colbase + wid * 48 + jt * 16 + lk4 * 4;
    size_t pbase = (size_t)(col0 >> 3) * 524288 + (col0 & 7);
#pragma unroll
    for (int rt = 0; rt < 4; ++rt) {
      int row = rows0 + rt * 16 + lr;
      u16x4 u;
#pragma unroll
      for (int r = 0; r < 4; ++r) u[r] = f2bf(acc[jt][rt][r] + bb[jt][r]);
      *(u16x4*)&qkvB[pbase + (size_t)row * 8] = u;
    }
  }
}

// ---------------- merged attention: blocks [0,4096) = ws=8, [4096,20480) = ws=4 ----------
// 1-wave blocks, XCD-chunked swizzles; qkvB8 16B-per-load reads; no barriers anywhere.
__global__ __launch_bounds__(64) void k_attn(const u16* __restrict__ qkvB,
                                             const float* __restrict__ bias8,
                                             const float* __restrict__ bias4,
                                             float* __restrict__ out) {
  __shared__ __align__(16) u16 sbuf[6912];   // 13824 B: attn8 = 2304 + 4608
  const int l = threadIdx.x;
  const int lr = l & 15, lk4 = l >> 4;
  const f32x4 z = {0.f, 0.f, 0.f, 0.f};
  const float scale = 0.17677669529663687f;  // 1/sqrt(32)

  if (blockIdx.x < 4096) {
    // ================= ws = 8 (group 1, channels 128..255) =================
    u16* vtg = sbuf;                 // V^T [e][m] stride 72 (2304 u16)
    u16* plg = sbuf + 2304;          // P [n][m] stride 72; reused as O f32 [64][33]
    const int lid = blockIdx.x;
    const int logical = (lid & 7) * 512 + (lid >> 3);  // bijective: 4096 = 8*512
    const int g = logical & 3;
    const int wj = (logical >> 2) & 7, wi = (logical >> 5) & 7, Bg = logical >> 8;
    const int h0 = wi * 8, w0 = wj * 8;

    const int c8q = 16 + g * 4 + lk4;   // q chans 128+g*32+lk4*8
    const int c8k = 48 + g * 4 + lk4;   // k chans 384+g*32+lk4*8
    short8 aq[4], bk[4];
#pragma unroll
    for (int tn = 0; tn < 4; ++tn) {
      int n = tn * 16 + lr;
      int m = m_of(Bg, h0 + (n >> 3), w0 + (n & 7));
      aq[tn] = ld8(qkvB, c8q, m);
      bk[tn] = ld8(qkvB, c8k, m);
    }
    // stage V^T: lane l owns token m=l; v chans 640+g*32+jj*8 (4 x 16B loads)
    {
      int m = m_of(Bg, h0 + (l >> 3), w0 + (l & 7));
#pragma unroll
      for (int jj = 0; jj < 4; ++jj) {
        short8 v = ld8(qkvB, 80 + g * 4 + jj, m);
#pragma unroll
        for (int j = 0; j < 8; ++j) vtg[(jj * 8 + j) * 72 + l] = (u16)v[j];
      }
    }
    // S = q k^T  (16 MFMAs)
    f32x4 s[4][4];
#pragma unroll
    for (int tn = 0; tn < 4; ++tn)
#pragma unroll
      for (int tm = 0; tm < 4; ++tm) s[tn][tm] = mfma16(aq[tn], bk[tm], z);

#pragma unroll
    for (int tn = 0; tn < 4; ++tn)
#pragma unroll
      for (int tm = 0; tm < 4; ++tm)
#pragma unroll
        for (int r = 0; r < 4; ++r) {
          int n = tn * 16 + lk4 * 4 + r, m = tm * 16 + lr;
          s[tn][tm][r] = s[tn][tm][r] * scale + bias8[(g * 64 + n) * 64 + m];
        }
    // softmax over m (row n lives in 16 lanes sharing l>>4)
    float invden[4][4];
#pragma unroll
    for (int tn = 0; tn < 4; ++tn)
#pragma unroll
      for (int r = 0; r < 4; ++r) {
        float mx = fmaxf(fmaxf(s[tn][0][r], s[tn][1][r]), fmaxf(s[tn][2][r], s[tn][3][r]));
#pragma unroll
        for (int d = 1; d < 16; d <<= 1) mx = fmaxf(mx, __shfl_xor(mx, d));
        float sum = 0.f;
#pragma unroll
        for (int tm = 0; tm < 4; ++tm) {
          float p = __expf(s[tn][tm][r] - mx);
          s[tn][tm][r] = p;
          sum += p;
        }
#pragma unroll
        for (int d = 1; d < 16; d <<= 1) sum += __shfl_xor(sum, d);
        invden[tn][r] = 1.f / sum;
      }
    // P -> LDS (bf16)
#pragma unroll
    for (int tn = 0; tn < 4; ++tn)
#pragma unroll
      for (int tm = 0; tm < 4; ++tm)
#pragma unroll
        for (int r = 0; r < 4; ++r)
          plg[(tn * 16 + lk4 * 4 + r) * 72 + tm * 16 + lr] = f2bf(s[tn][tm][r]);
    wave_lds_fence();
    // O = P V  (16 MFMAs)
    f32x4 o[4][2];
#pragma unroll
    for (int tn = 0; tn < 4; ++tn) { o[tn][0] = z; o[tn][1] = z; }
#pragma unroll
    for (int kc = 0; kc < 2; ++kc) {
      short8 pa[4], vb[2];
#pragma unroll
      for (int tn = 0; tn < 4; ++tn)
        pa[tn] = *(const short8*)&plg[(tn * 16 + lr) * 72 + kc * 32 + lk4 * 8];
#pragma unroll
      for (int te = 0; te < 2; ++te)
        vb[te] = *(const short8*)&vtg[(te * 16 + lr) * 72 + kc * 32 + lk4 * 8];
#pragma unroll
      for (int tn = 0; tn < 4; ++tn)
#pragma unroll
        for (int te = 0; te < 2; ++te) o[tn][te] = mfma16(pa[tn], vb[te], o[tn][te]);
    }
    wave_lds_fence();
    // scale by 1/denom, transpose O through LDS (overlay on plg)
    float* ol = (float*)plg;  // [64][33]
#pragma unroll
    for (int tn = 0; tn < 4; ++tn)
#pragma unroll
      for (int te = 0; te < 2; ++te)
#pragma unroll
        for (int r = 0; r < 4; ++r) {
          int n = tn * 16 + lk4 * 4 + r;
          ol[n * 33 + te * 16 + lr] = o[tn][te][r] * invden[tn][r];
        }
    wave_lds_fence();
    // store: lane = token, loop e -> 32B-chunk runs along w
    {
      int h = h0 + (l >> 3), w = w0 + (l & 7);
      size_t base = ((size_t)(Bg >> 2)) * 4194304 + (size_t)(((Bg & 3) * 2 + (h >> 5))) * 131072 +
                    (size_t)(((h >> 2) & 7)) * 16384 + (size_t)((h & 3) * 64 + w);
#pragma unroll
      for (int e = 0; e < 32; ++e) {
        int c = 128 + g * 32 + e;
        size_t idx = base + (size_t)(c >> 6) * 1048576 + (size_t)((c >> 3) & 7) * 2048 +
                     (size_t)(c & 7) * 256;
        out[idx] = ol[l * 33 + e];
      }
    }
  } else {
    // ================= ws = 4 (group 0, channels 0..127) =================
    u16* vtw = sbuf;                       // V^T [e][m0..32] stride 40 (1280 u16)
    u16* plw = sbuf + 1280;                // P [n][m0..32] stride 40 (640 u16)
    float* olw = (float*)(sbuf + 1920);    // O [16][33] f32 (3840%4==0)
    const int lid = blockIdx.x - 4096;
    const int logical = (lid & 7) * 2048 + (lid >> 3);  // bijective: 16384 = 8*2048
    const int g = logical & 3;
    const int wid2 = logical >> 2;         // window id in [0,4096)
    const int Bg = wid2 >> 8, wi = (wid2 >> 4) & 15, wj = wid2 & 15;
    const int h0 = wi * 4, w0 = wj * 4;
    const short8 z8 = {0, 0, 0, 0, 0, 0, 0, 0};

    // zero the K-padding (cols 16..31) of P and V^T
    {
      u16x4 z4 = {0, 0, 0, 0};
      *(u16x4*)&plw[(l & 15) * 40 + 16 + (l >> 4) * 4] = z4;
      *(short8*)&vtw[(l >> 1) * 40 + 16 + (l & 1) * 8] = z8;
    }
    const int mq = m_of(Bg, h0 + (lr >> 2), w0 + (lr & 3));

    short8 aq = ld8(qkvB, g * 4 + lk4, mq);          // q chans g*32+lk4*8
    short8 bk = ld8(qkvB, 32 + g * 4 + lk4, mq);     // k chans 256+g*32+lk4*8
    {
      short8 v = ld8(qkvB, 64 + g * 4 + lk4, mq);    // v chans 512+g*32+lk4*8
#pragma unroll
      for (int j = 0; j < 8; ++j) vtw[(lk4 * 8 + j) * 40 + lr] = (u16)v[j];
    }
    // S (1 MFMA), C rows n = lk4*4+r, cols m = lr
    f32x4 s = mfma16(aq, bk, z);
#pragma unroll
    for (int r = 0; r < 4; ++r) {
      int n = lk4 * 4 + r;
      s[r] = s[r] * scale + bias4[(g * 16 + n) * 16 + lr];
    }
    float invden[4];
#pragma unroll
    for (int r = 0; r < 4; ++r) {
      float mx = s[r];
#pragma unroll
      for (int d = 1; d < 16; d <<= 1) mx = fmaxf(mx, __shfl_xor(mx, d));
      float p = __expf(s[r] - mx);
      s[r] = p;
      float sum = p;
#pragma unroll
      for (int d = 1; d < 16; d <<= 1) sum += __shfl_xor(sum, d);
      invden[r] = 1.f / sum;
    }
    // P -> LDS
#pragma unroll
    for (int r = 0; r < 4; ++r) plw[(lk4 * 4 + r) * 40 + lr] = f2bf(s[r]);
    wave_lds_fence();
    // O = P V : 2 MFMAs (te halves), K zero-padded to 32
    f32x4 o[2];
#pragma unroll
    for (int te = 0; te < 2; ++te) {
      short8 pa = *(const short8*)&plw[lr * 40 + lk4 * 8];
      short8 vb = *(const short8*)&vtw[(te * 16 + lr) * 40 + lk4 * 8];
      o[te] = mfma16(pa, vb, z);
    }
#pragma unroll
    for (int te = 0; te < 2; ++te)
#pragma unroll
      for (int r = 0; r < 4; ++r) {
        int n = lk4 * 4 + r;
        olw[n * 33 + te * 16 + lr] = o[te][r] * invden[r];
      }
    wave_lds_fence();
    // store: lane = (token lr) x (e-chunk lk4)
    {
      int h = h0 + (lr >> 2), w = w0 + (lr & 3);
      size_t base = ((size_t)(Bg >> 2)) * 4194304 +
                    (size_t)(((Bg & 3) * 2 + (h >> 5))) * 131072 +
                    (size_t)(((h >> 2) & 7)) * 16384 + (size_t)((h & 3) * 64 + w);
#pragma unroll
      for (int ee = 0; ee < 8; ++ee) {
        int e = lk4 * 8 + ee;
        int c = g * 32 + e;
        size_t idx = base + (size_t)(c >> 6) * 1048576 + (size_t)((c >> 3) & 7) * 2048 +
                     (size_t)(c & 7) * 256;
        out[idx] = olw[lr * 33 + e];
      }
    }
  }
}

extern "C" void kernel_launch(void* const* d_in, const int* in_sizes, int n_in,
                              void* d_out, int out_size, void* d_ws, size_t ws_size,
                              hipStream_t stream) {
  const float* x = (const float*)d_in[0];
  const float* qkv_w = (const float*)d_in[1];
  const float* qkv_b = (const float*)d_in[2];
  const float* t0 = (const float*)d_in[3];
  const float* t1 = (const float*)d_in[4];
  float* out = (float*)d_out;
  char* ws = (char*)d_ws;

  u16* qkvB = (u16*)ws;                         // 96 planes * 524288 u16 = 100663296 B
  u16* wbp = (u16*)(ws + 100663296);            // 196608 u16       = 393216 B
  float* bias8 = (float*)(ws + 101056512);      // 4*64*64*4        = 65536 B
  float* bias4 = (float*)(ws + 101122048);      // 4*16*16*4        = 4096 B

  k_prep<<<256, 256, 0, stream>>>(qkv_w, t0, t1, wbp, bias4, bias8);
  k_gemm<<<2048, 512, 0, stream>>>(x, wbp, qkv_b, qkvB);
  k_attn<<<20480, 64, 0, stream>>>(qkvB, bias8, bias4, out);
}

// Round 21
// 87.374 us; speedup vs baseline: 1.1326x; 1.0157x over previous
//
#include <hip/hip_runtime.h>

typedef unsigned short u16;
typedef unsigned int u32;
typedef __attribute__((ext_vector_type(8))) short short8;   // 8 bf16 (MFMA A/B frag)
typedef __attribute__((ext_vector_type(4))) float f32x4;    // MFMA C/D frag
typedef __attribute__((ext_vector_type(4))) float fvec4;
typedef __attribute__((ext_vector_type(4))) u16 u16x4;

typedef __attribute__((address_space(1))) void gvoid;
typedef __attribute__((address_space(3))) void lvoid;

__device__ __forceinline__ u16 f2bf(float f) {
  u32 u = __float_as_uint(f);
  u += 0x7FFFu + ((u >> 16) & 1u);   // RTNE
  return (u16)(u >> 16);
}

// async global->LDS DMA, 16B/lane: LDS dest = uniform base + lane*16, global src per-lane.
__device__ __forceinline__ void gl16(const u16* g, u16* d) {
  __builtin_amdgcn_global_load_lds((gvoid*)g, (lvoid*)d, 16, 0, 0);
}

// wave-local LDS fence: drains this wave's ds ops only (lgkmcnt), does NOT touch vmcnt.
__device__ __forceinline__ void wave_lds_fence() {
  asm volatile("s_waitcnt lgkmcnt(0)" ::: "memory");
  __builtin_amdgcn_sched_barrier(0);
}

// memory row index of token (Bg,h,w); rows of x are 256 elems.
__device__ __forceinline__ int m_of(int Bg, int h, int w) {
  return ((Bg >> 2) << 14) | ((h & 3) << 12) | ((((Bg & 3) << 1) | (h >> 5)) << 9) |
         (((h >> 2) & 7) << 6) | w;
}

__device__ __forceinline__ f32x4 mfma16(short8 a, short8 b, f32x4 c) {
  return __builtin_amdgcn_mfma_f32_16x16x32_bf16(a, b, c, 0, 0, 0);
}

// qkvB8 layout: element (channel c, token m) at (c>>3)*524288 + m*8 + (c&7).
// ld8: 8 consecutive channels (c8*8 .. c8*8+7) at token m -> ONE 16B load.
__device__ __forceinline__ short8 ld8(const u16* __restrict__ qb, int c8, int m) {
  return *(const short8*)(qb + (size_t)c8 * 524288 + (size_t)m * 8);
}

// ---------------- prep: pack W into DMA-ready swizzled order + bias matrices --------------
__global__ void k_prep(const float* __restrict__ qkv_w, const float* __restrict__ t0,
                       const float* __restrict__ t1, u16* __restrict__ wbp,
                       float* __restrict__ bias4, float* __restrict__ bias8) {
  int tid = blockIdx.x * 256 + threadIdx.x;
  int stride = gridDim.x * 256;
  for (int i = tid; i < 196608; i += stride) {
    int nhc = i / 12288;              // (nh*8 + chunk) in [0,16)
    int rem = i - nhc * 12288;
    int p = rem >> 3, e = rem & 7;
    int cu = p >> 2;
    int su = (p & 3) ^ ((cu >> 1) & 3);
    int col = (nhc >> 3) * 384 + cu;
    int k = (nhc & 7) * 32 + su * 8 + e;
    wbp[i] = f2bf(qkv_w[col * 256 + k]);
  }
  for (int i = tid; i < 4 * 64 * 64; i += stride) {
    int g = i >> 12, n = (i >> 6) & 63, m = i & 63;
    int di = (n >> 3) - (m >> 3) + 7, dj = (n & 7) - (m & 7) + 7;
    bias8[i] = t1[(di * 15 + dj) * 4 + g];
  }
  for (int i = tid; i < 4 * 16 * 16; i += stride) {
    int g = i >> 8, n = (i >> 4) & 15, m = i & 15;
    int di = (n >> 2) - (m >> 2) + 3, dj = (n & 3) - (m & 3) + 3;
    bias4[i] = t0[(di * 7 + dj) * 4 + g];
  }
}

// ---------------- QKV GEMM: [65536 x 256] x [256 x 768] -> qkvB8 blocked layout -----------
// ROUND-18/20 PROVEN: grid 2048, pairing swizzle; FULL As 64x256 (32KB, slot-swizzled,
// single prologue barrier, free-run loop); B via global_load_lds from pre-swizzled wbp,
// per-wave dbuf slabs, 2-deep counted vmcnt(3); LDS exactly 80KB; 8-chan-plane epilogue.
__global__ __launch_bounds__(512, 4) void k_gemm(const float* __restrict__ x,
                                                 const u16* __restrict__ wbp,
                                                 const float* __restrict__ qkv_b,
                                                 u16* __restrict__ qkvB) {
  __shared__ __align__(16) u16 As[64 * 256];       // 32768 B, XOR slot-swizzled, full K
  __shared__ __align__(16) u16 Bs[2 * 8 * 1536];   // 49152 B: [buf][wave][48 cols x 32 k]
  const int t = threadIdx.x;
  const int wid = t >> 6, l = t & 63;
  const int lr = l & 15, lk4 = l >> 4;
  const int mt = ((blockIdx.x >> 4) << 3) | (blockIdx.x & 7);  // pairing swizzle
  const int nh = (blockIdx.x >> 3) & 1;
  const size_t xbase = (size_t)mt * 64 * 256;
  const int colbase = nh * 384;            // this block's first output col

  // B DMA geometry: src has per-lane l*8; dest base is wave-uniform (HW adds lane*16B)
  const u16* wsrc = wbp + (size_t)(nh * 8) * 12288 + (wid * 192 + l) * 8;
  u16* bdst = &Bs[wid * 1536];

  // ---- (1) bias pre-load: OLDEST VMEM, pinned before any DMA ----
  fvec4 bb[3];
#pragma unroll
  for (int jt = 0; jt < 3; ++jt)
    bb[jt] = *(const fvec4*)(qkv_b + colbase + wid * 48 + jt * 16 + lk4 * 4);
  asm volatile("" ::: "memory");           // bias loads stay above everything below

  // ---- (2) DMA chunk0 -> buf0, chunk1 -> buf1 ----
#pragma unroll
  for (int j = 0; j < 3; ++j) gl16(wsrc + j * 512, bdst + j * 512);
#pragma unroll
  for (int j = 0; j < 3; ++j) gl16(wsrc + 12288 + j * 512, bdst + 12288 + j * 512);
  asm volatile("" ::: "memory");           // pin DMA issue order before x loads

  // ---- (3) stage FULL As: thread covers col (t&63)*4, rows wid + it*8 ----
  {
    const int cc = (l & 63) * 4;           // u16 col, multiple of 4
    const int slot = cc >> 3, half = cc & 7;
    const float* xp = x + xbase + (size_t)wid * 256 + cc;
#pragma unroll
    for (int it = 0; it < 8; ++it) {
      fvec4 v = *(const fvec4*)(xp + it * 8 * 256);
      int r = wid + it * 8;
      u16x4 u;
      u[0] = f2bf(v[0]); u[1] = f2bf(v[1]); u[2] = f2bf(v[2]); u[3] = f2bf(v[3]);
      *(u16x4*)&As[r * 256 + ((slot ^ (r & 7)) << 3) + half] = u;
    }
  }
  asm volatile("s_waitcnt lgkmcnt(0)" ::: "memory");
  __builtin_amdgcn_s_barrier();            // As visible — the ONLY barrier in this kernel

  f32x4 acc[3][4];
  const f32x4 z = {0.f, 0.f, 0.f, 0.f};
#pragma unroll
  for (int jt = 0; jt < 3; ++jt)
#pragma unroll
    for (int rt = 0; rt < 4; ++rt) acc[jt][rt] = z;

  const int bswz = (lr >> 1) & 3;          // B-read slot swizzle
#pragma unroll
  for (int ci = 0; ci < 8; ++ci) {
    const int buf = ci & 1;
    // counted wait: chunk ci is the 2nd-newest DMA group in FIFO -> vmcnt(3) retires it;
    // chunk ci+1 (newest, 3 ops) stays in flight. Last iter: full drain.
    if (ci == 7) asm volatile("s_waitcnt vmcnt(0)" ::: "memory");
    else         asm volatile("s_waitcnt vmcnt(3)" ::: "memory");
    __builtin_amdgcn_sched_barrier(0);
    // reads (LDS only)
    short8 a[4], b[3];
    const int kslot = ci * 4 + lk4;        // 0..31 within full 256-K row
#pragma unroll
    for (int rt = 0; rt < 4; ++rt) {
      int row = rt * 16 + lr;
      a[rt] = *(const short8*)&As[row * 256 + ((kslot ^ (row & 7)) << 3)];
    }
#pragma unroll
    for (int jt = 0; jt < 3; ++jt)
      b[jt] = *(const short8*)&Bs[buf * 12288 + wid * 1536 +
                                  (jt * 16 + lr) * 32 + ((lk4 ^ bswz) * 8)];
    // drain reads into regs -> WAR-safe to DMA into this buffer below
    asm volatile("s_waitcnt lgkmcnt(0)" ::: "memory");
    __builtin_amdgcn_sched_barrier(0);
    if (ci < 6) {                          // issue chunk ci+2 into buf(ci&1)
      const u16* s = wsrc + (size_t)(ci + 2) * 12288;
      u16* d = bdst + buf * 12288;
#pragma unroll
      for (int j = 0; j < 3; ++j) gl16(s + j * 512, d + j * 512);
    }
    __builtin_amdgcn_sched_barrier(0);
#pragma unroll
    for (int jt = 0; jt < 3; ++jt)
#pragma unroll
      for (int rt = 0; rt < 4; ++rt)
        acc[jt][rt] = mfma16(b[jt], a[rt], acc[jt][rt]);  // reg-dim = col
  }

  // ---- epilogue: + bias, 8-chan-plane layout: store instr fills 2 planes x 256B ----
  const int rows0 = mt * 64;
#pragma unroll
  for (int jt = 0; jt < 3; ++jt) {
    int col0 = colbase + wid * 48 + jt * 16 + lk4 * 4;
    size_t pbase = (size_t)(col0 >> 3) * 524288 + (col0 & 7);
#pragma unroll
    for (int rt = 0; rt < 4; ++rt) {
      int row = rows0 + rt * 16 + lr;
      u16x4 u;
#pragma unroll
      for (int r = 0; r < 4; ++r) u[r] = f2bf(acc[jt][rt][r] + bb[jt][r]);
      *(u16x4*)&qkvB[pbase + (size_t)row * 8] = u;
    }
  }
}

// ---------------- merged attention ------------------------------------------------------
// blocks [0,8192): ws=8 n-half blocks (window x head x n-half); [8192,24576): ws=4.
// 1-wave blocks, 9216B LDS carve -> 17 blocks/CU (was 11). No barriers anywhere.
__global__ __launch_bounds__(64) void k_attn(const u16* __restrict__ qkvB,
                                             const float* __restrict__ bias8,
                                             const float* __restrict__ bias4,
                                             float* __restrict__ out) {
  __shared__ __align__(16) u16 sbuf[4608];   // 9216 B
  const int l = threadIdx.x;
  const int lr = l & 15, lk4 = l >> 4;
  const f32x4 z = {0.f, 0.f, 0.f, 0.f};
  const float scale = 0.17677669529663687f;  // 1/sqrt(32)

  if (blockIdx.x < 8192) {
    // ============ ws = 8, n-half blocks (group 1, channels 128..255) ============
    u16* vtg = sbuf;                 // V^T [32 e][72 m] (2304 u16)
    u16* plg = sbuf + 2304;          // P [32 n][72 m]; reused as O f32 [32][33]
    const int lid = blockIdx.x;
    const int logical = (lid & 7) * 1024 + (lid >> 3);  // bijective: 8192 = 8*1024
    const int nh2 = logical & 1;             // n-half (fastest: halves share K/V in L2)
    const int g = (logical >> 1) & 3;
    const int wj = (logical >> 3) & 7, wi = (logical >> 6) & 7, Bg = logical >> 9;
    const int h0 = wi * 8, w0 = wj * 8;

    const int c8q = 16 + g * 4 + lk4;   // q chans 128+g*32+lk4*8
    const int c8k = 48 + g * 4 + lk4;   // k chans 384+g*32+lk4*8
    // Q frags for this n-half; K frags for ALL m
    short8 aq[2], bk[4];
#pragma unroll
    for (int tn = 0; tn < 2; ++tn) {
      int n = nh2 * 32 + tn * 16 + lr;
      aq[tn] = ld8(qkvB, c8q, m_of(Bg, h0 + (n >> 3), w0 + (n & 7)));
    }
#pragma unroll
    for (int tm = 0; tm < 4; ++tm) {
      int m = tm * 16 + lr;
      bk[tm] = ld8(qkvB, c8k, m_of(Bg, h0 + (m >> 3), w0 + (m & 7)));
    }
    // stage V^T: lane l owns token m=l (all 64 m); v chans 640+g*32+jj*8
    {
      int m = m_of(Bg, h0 + (l >> 3), w0 + (l & 7));
#pragma unroll
      for (int jj = 0; jj < 4; ++jj) {
        short8 v = ld8(qkvB, 80 + g * 4 + jj, m);
#pragma unroll
        for (int j = 0; j < 8; ++j) vtg[(jj * 8 + j) * 72 + l] = (u16)v[j];
      }
    }
    // S = q k^T  (8 MFMAs): s[tn][tm] rows n = nh2*32+tn*16+lk4*4+r, cols m = tm*16+lr
    f32x4 s[2][4];
#pragma unroll
    for (int tn = 0; tn < 2; ++tn)
#pragma unroll
      for (int tm = 0; tm < 4; ++tm) s[tn][tm] = mfma16(aq[tn], bk[tm], z);

#pragma unroll
    for (int tn = 0; tn < 2; ++tn)
#pragma unroll
      for (int tm = 0; tm < 4; ++tm)
#pragma unroll
        for (int r = 0; r < 4; ++r) {
          int n = nh2 * 32 + tn * 16 + lk4 * 4 + r, m = tm * 16 + lr;
          s[tn][tm][r] = s[tn][tm][r] * scale + bias8[(g * 64 + n) * 64 + m];
        }
    // softmax over m (row n lives in 16 lanes sharing l>>4)
    float invden[2][4];
#pragma unroll
    for (int tn = 0; tn < 2; ++tn)
#pragma unroll
      for (int r = 0; r < 4; ++r) {
        float mx = fmaxf(fmaxf(s[tn][0][r], s[tn][1][r]), fmaxf(s[tn][2][r], s[tn][3][r]));
#pragma unroll
        for (int d = 1; d < 16; d <<= 1) mx = fmaxf(mx, __shfl_xor(mx, d));
        float sum = 0.f;
#pragma unroll
        for (int tm = 0; tm < 4; ++tm) {
          float p = __expf(s[tn][tm][r] - mx);
          s[tn][tm][r] = p;
          sum += p;
        }
#pragma unroll
        for (int d = 1; d < 16; d <<= 1) sum += __shfl_xor(sum, d);
        invden[tn][r] = 1.f / sum;
      }
    // P -> LDS (bf16), local rows 0..31
#pragma unroll
    for (int tn = 0; tn < 2; ++tn)
#pragma unroll
      for (int tm = 0; tm < 4; ++tm)
#pragma unroll
        for (int r = 0; r < 4; ++r)
          plg[(tn * 16 + lk4 * 4 + r) * 72 + tm * 16 + lr] = f2bf(s[tn][tm][r]);
    wave_lds_fence();
    // O = P V  (8 MFMAs)
    f32x4 o[2][2];
#pragma unroll
    for (int tn = 0; tn < 2; ++tn) { o[tn][0] = z; o[tn][1] = z; }
#pragma unroll
    for (int kc = 0; kc < 2; ++kc) {
      short8 pa[2], vb[2];
#pragma unroll
      for (int tn = 0; tn < 2; ++tn)
        pa[tn] = *(const short8*)&plg[(tn * 16 + lr) * 72 + kc * 32 + lk4 * 8];
#pragma unroll
      for (int te = 0; te < 2; ++te)
        vb[te] = *(const short8*)&vtg[(te * 16 + lr) * 72 + kc * 32 + lk4 * 8];
#pragma unroll
      for (int tn = 0; tn < 2; ++tn)
#pragma unroll
        for (int te = 0; te < 2; ++te) o[tn][te] = mfma16(pa[tn], vb[te], o[tn][te]);
    }
    wave_lds_fence();
    // scale by 1/denom, transpose O through LDS (overlay on plg): [32][33] f32
    float* ol = (float*)plg;
#pragma unroll
    for (int tn = 0; tn < 2; ++tn)
#pragma unroll
      for (int te = 0; te < 2; ++te)
#pragma unroll
        for (int r = 0; r < 4; ++r) {
          int nloc = tn * 16 + lk4 * 4 + r;
          ol[nloc * 33 + te * 16 + lr] = o[tn][te][r] * invden[tn][r];
        }
    wave_lds_fence();
    // store: lane covers (token nloc = l&31) x (e-half = (l>>5)*16); 16 e's each
    {
      int nloc = l & 31, e0 = (l >> 5) * 16;
      int n = nh2 * 32 + nloc;
      int h = h0 + (n >> 3), w = w0 + (n & 7);
      size_t base = ((size_t)(Bg >> 2)) * 4194304 + (size_t)(((Bg & 3) * 2 + (h >> 5))) * 131072 +
                    (size_t)(((h >> 2) & 7)) * 16384 + (size_t)((h & 3) * 64 + w);
      const float* orow = ol + nloc * 33;
#pragma unroll
      for (int ee = 0; ee < 16; ++ee) {
        int c = 128 + g * 32 + e0 + ee;
        size_t idx = base + (size_t)(c >> 6) * 1048576 + (size_t)((c >> 3) & 7) * 2048 +
                     (size_t)(c & 7) * 256;
        out[idx] = orow[e0 + ee];
      }
    }
  } else {
    // ================= ws = 4 (group 0, channels 0..127) =================
    u16* vtw = sbuf;                       // V^T [e][m0..32] stride 40 (1280 u16)
    u16* plw = sbuf + 1280;                // P [n][m0..32] stride 40 (640 u16)
    float* olw = (float*)(sbuf + 1920);    // O [16][33] f32 (3840%4==0; 1920+1056*2<=4608)
    const int lid = blockIdx.x - 8192;
    const int logical = (lid & 7) * 2048 + (lid >> 3);  // bijective: 16384 = 8*2048
    const int g = logical & 3;
    const int wid2 = logical >> 2;         // window id in [0,4096)
    const int Bg = wid2 >> 8, wi = (wid2 >> 4) & 15, wj = wid2 & 15;
    const int h0 = wi * 4, w0 = wj * 4;
    const short8 z8 = {0, 0, 0, 0, 0, 0, 0, 0};

    // zero the K-padding (cols 16..31) of P and V^T
    {
      u16x4 z4 = {0, 0, 0, 0};
      *(u16x4*)&plw[(l & 15) * 40 + 16 + (l >> 4) * 4] = z4;
      *(short8*)&vtw[(l >> 1) * 40 + 16 + (l & 1) * 8] = z8;
    }
    const int mq = m_of(Bg, h0 + (lr >> 2), w0 + (lr & 3));

    short8 aq = ld8(qkvB, g * 4 + lk4, mq);          // q chans g*32+lk4*8
    short8 bk = ld8(qkvB, 32 + g * 4 + lk4, mq);     // k chans 256+g*32+lk4*8
    {
      short8 v = ld8(qkvB, 64 + g * 4 + lk4, mq);    // v chans 512+g*32+lk4*8
#pragma unroll
      for (int j = 0; j < 8; ++j) vtw[(lk4 * 8 + j) * 40 + lr] = (u16)v[j];
    }
    // S (1 MFMA), C rows n = lk4*4+r, cols m = lr
    f32x4 s = mfma16(aq, bk, z);
#pragma unroll
    for (int r = 0; r < 4; ++r) {
      int n = lk4 * 4 + r;
      s[r] = s[r] * scale + bias4[(g * 16 + n) * 16 + lr];
    }
    float invden[4];
#pragma unroll
    for (int r = 0; r < 4; ++r) {
      float mx = s[r];
#pragma unroll
      for (int d = 1; d < 16; d <<= 1) mx = fmaxf(mx, __shfl_xor(mx, d));
      float p = __expf(s[r] - mx);
      s[r] = p;
      float sum = p;
#pragma unroll
      for (int d = 1; d < 16; d <<= 1) sum += __shfl_xor(sum, d);
      invden[r] = 1.f / sum;
    }
    // P -> LDS
#pragma unroll
    for (int r = 0; r < 4; ++r) plw[(lk4 * 4 + r) * 40 + lr] = f2bf(s[r]);
    wave_lds_fence();
    // O = P V : 2 MFMAs (te halves), K zero-padded to 32
    f32x4 o[2];
#pragma unroll
    for (int te = 0; te < 2; ++te) {
      short8 pa = *(const short8*)&plw[lr * 40 + lk4 * 8];
      short8 vb = *(const short8*)&vtw[(te * 16 + lr) * 40 + lk4 * 8];
      o[te] = mfma16(pa, vb, z);
    }
#pragma unroll
    for (int te = 0; te < 2; ++te)
#pragma unroll
      for (int r = 0; r < 4; ++r) {
        int n = lk4 * 4 + r;
        olw[n * 33 + te * 16 + lr] = o[te][r] * invden[r];
      }
    wave_lds_fence();
    // store: lane = (token lr) x (e-chunk lk4)
    {
      int h = h0 + (lr >> 2), w = w0 + (lr & 3);
      size_t base = ((size_t)(Bg >> 2)) * 4194304 +
                    (size_t)(((Bg & 3) * 2 + (h >> 5))) * 131072 +
                    (size_t)(((h >> 2) & 7)) * 16384 + (size_t)((h & 3) * 64 + w);
#pragma unroll
      for (int ee = 0; ee < 8; ++ee) {
        int e = lk4 * 8 + ee;
        int c = g * 32 + e;
        size_t idx = base + (size_t)(c >> 6) * 1048576 + (size_t)((c >> 3) & 7) * 2048 +
                     (size_t)(c & 7) * 256;
        out[idx] = olw[lr * 33 + e];
      }
    }
  }
}

extern "C" void kernel_launch(void* const* d_in, const int* in_sizes, int n_in,
                              void* d_out, int out_size, void* d_ws, size_t ws_size,
                              hipStream_t stream) {
  const float* x = (const float*)d_in[0];
  const float* qkv_w = (const float*)d_in[1];
  const float* qkv_b = (const float*)d_in[2];
  const float* t0 = (const float*)d_in[3];
  const float* t1 = (const float*)d_in[4];
  float* out = (float*)d_out;
  char* ws = (char*)d_ws;

  u16* qkvB = (u16*)ws;                         // 96 planes * 524288 u16 = 100663296 B
  u16* wbp = (u16*)(ws + 100663296);            // 196608 u16       = 393216 B
  float* bias8 = (float*)(ws + 101056512);      // 4*64*64*4        = 65536 B
  float* bias4 = (float*)(ws + 101122048);      // 4*16*16*4        = 4096 B

  k_prep<<<256, 256, 0, stream>>>(qkv_w, t0, t1, wbp, bias4, bias8);
  k_gemm<<<2048, 512, 0, stream>>>(x, wbp, qkv_b, qkvB);
  k_attn<<<24576, 64, 0, stream>>>(qkvB, bias8, bias4, out);
}

// Round 22
// 84.639 us; speedup vs baseline: 1.1692x; 1.0323x over previous
//
#include <hip/hip_runtime.h>

typedef unsigned short u16;
typedef unsigned int u32;
typedef __attribute__((ext_vector_type(8))) short short8;   // 8 bf16 (MFMA A/B frag)
typedef __attribute__((ext_vector_type(4))) float f32x4;    // MFMA C/D frag
typedef __attribute__((ext_vector_type(4))) float fvec4;
typedef __attribute__((ext_vector_type(4))) u16 u16x4;

typedef __attribute__((address_space(1))) void gvoid;
typedef __attribute__((address_space(3))) void lvoid;

__device__ __forceinline__ u16 f2bf(float f) {
  u32 u = __float_as_uint(f);
  u += 0x7FFFu + ((u >> 16) & 1u);   // RTNE
  return (u16)(u >> 16);
}

// async global->LDS DMA, 16B/lane: LDS dest = uniform base + lane*16, global src per-lane.
__device__ __forceinline__ void gl16(const u16* g, u16* d) {
  __builtin_amdgcn_global_load_lds((gvoid*)g, (lvoid*)d, 16, 0, 0);
}

// wave-local LDS fence: drains this wave's ds ops only (lgkmcnt), does NOT touch vmcnt.
__device__ __forceinline__ void wave_lds_fence() {
  asm volatile("s_waitcnt lgkmcnt(0)" ::: "memory");
  __builtin_amdgcn_sched_barrier(0);
}

// memory row index of token (Bg,h,w); rows of x are 256 elems.
__device__ __forceinline__ int m_of(int Bg, int h, int w) {
  return ((Bg >> 2) << 14) | ((h & 3) << 12) | ((((Bg & 3) << 1) | (h >> 5)) << 9) |
         (((h >> 2) & 7) << 6) | w;
}

__device__ __forceinline__ f32x4 mfma16(short8 a, short8 b, f32x4 c) {
  return __builtin_amdgcn_mfma_f32_16x16x32_bf16(a, b, c, 0, 0, 0);
}

// qkvB8 layout: element (channel c, token m) at (c>>3)*524288 + m*8 + (c&7).
// ld8: 8 consecutive channels (c8*8 .. c8*8+7) at token m -> ONE 16B load.
__device__ __forceinline__ short8 ld8(const u16* __restrict__ qb, int c8, int m) {
  return *(const short8*)(qb + (size_t)c8 * 524288 + (size_t)m * 8);
}

// V^T fragment gather (ws=8): channel ce, window tokens m0..m0+7 (m0%8==0 -> one window
// row -> memory-contiguous, stride 8 u16 within the plane). 8 scalar L2-hit loads.
__device__ __forceinline__ short8 gatherVT8(const u16* __restrict__ qb, int ce,
                                            int Bg, int h0, int w0, int m0) {
  const u16* p = qb + (size_t)(ce >> 3) * 524288 + (ce & 7) +
                 (size_t)m_of(Bg, h0 + (m0 >> 3), w0) * 8;
  union { u16 h[8]; short8 v; } u;
#pragma unroll
  for (int j = 0; j < 8; ++j) u.h[j] = p[j * 8];
  return u.v;
}

// ---------------- prep: pack W into DMA-ready swizzled order + bias matrices --------------
__global__ void k_prep(const float* __restrict__ qkv_w, const float* __restrict__ t0,
                       const float* __restrict__ t1, u16* __restrict__ wbp,
                       float* __restrict__ bias4, float* __restrict__ bias8) {
  int tid = blockIdx.x * 256 + threadIdx.x;
  int stride = gridDim.x * 256;
  for (int i = tid; i < 196608; i += stride) {
    int nhc = i / 12288;              // (nh*8 + chunk) in [0,16)
    int rem = i - nhc * 12288;
    int p = rem >> 3, e = rem & 7;
    int cu = p >> 2;
    int su = (p & 3) ^ ((cu >> 1) & 3);
    int col = (nhc >> 3) * 384 + cu;
    int k = (nhc & 7) * 32 + su * 8 + e;
    wbp[i] = f2bf(qkv_w[col * 256 + k]);
  }
  for (int i = tid; i < 4 * 64 * 64; i += stride) {
    int g = i >> 12, n = (i >> 6) & 63, m = i & 63;
    int di = (n >> 3) - (m >> 3) + 7, dj = (n & 7) - (m & 7) + 7;
    bias8[i] = t1[(di * 15 + dj) * 4 + g];
  }
  for (int i = tid; i < 4 * 16 * 16; i += stride) {
    int g = i >> 8, n = (i >> 4) & 15, m = i & 15;
    int di = (n >> 2) - (m >> 2) + 3, dj = (n & 3) - (m & 3) + 3;
    bias4[i] = t0[(di * 7 + dj) * 4 + g];
  }
}

// ---------------- QKV GEMM: [65536 x 256] x [256 x 768] -> qkvB8 blocked layout -----------
// r18/20 base: grid 2048, pairing swizzle; FULL As 64x256 (32KB, slot-swizzled, single
// prologue barrier); per-wave dbuf DMA slabs, 2-deep counted vmcnt(3); LDS exactly 80KB.
// r22: loop reordered reads -> MFMAs -> DMA (MFMA consumption closes WAR; no full lgkm
// drain on the critical path; sched_barrier pins DMA after the MFMA block).
__global__ __launch_bounds__(512, 4) void k_gemm(const float* __restrict__ x,
                                                 const u16* __restrict__ wbp,
                                                 const float* __restrict__ qkv_b,
                                                 u16* __restrict__ qkvB) {
  __shared__ __align__(16) u16 As[64 * 256];       // 32768 B, XOR slot-swizzled, full K
  __shared__ __align__(16) u16 Bs[2 * 8 * 1536];   // 49152 B: [buf][wave][48 cols x 32 k]
  const int t = threadIdx.x;
  const int wid = t >> 6, l = t & 63;
  const int lr = l & 15, lk4 = l >> 4;
  const int mt = ((blockIdx.x >> 4) << 3) | (blockIdx.x & 7);  // pairing swizzle
  const int nh = (blockIdx.x >> 3) & 1;
  const size_t xbase = (size_t)mt * 64 * 256;
  const int colbase = nh * 384;            // this block's first output col

  // B DMA geometry: src has per-lane l*8; dest base is wave-uniform (HW adds lane*16B)
  const u16* wsrc = wbp + (size_t)(nh * 8) * 12288 + (wid * 192 + l) * 8;
  u16* bdst = &Bs[wid * 1536];

  // ---- (1) bias pre-load: OLDEST VMEM, pinned before any DMA ----
  fvec4 bb[3];
#pragma unroll
  for (int jt = 0; jt < 3; ++jt)
    bb[jt] = *(const fvec4*)(qkv_b + colbase + wid * 48 + jt * 16 + lk4 * 4);
  asm volatile("" ::: "memory");           // bias loads stay above everything below

  // ---- (2) DMA chunk0 -> buf0, chunk1 -> buf1 ----
#pragma unroll
  for (int j = 0; j < 3; ++j) gl16(wsrc + j * 512, bdst + j * 512);
#pragma unroll
  for (int j = 0; j < 3; ++j) gl16(wsrc + 12288 + j * 512, bdst + 12288 + j * 512);
  asm volatile("" ::: "memory");           // pin DMA issue order before x loads

  // ---- (3) stage FULL As: thread covers col (t&63)*4, rows wid + it*8 ----
  {
    const int cc = (l & 63) * 4;           // u16 col, multiple of 4
    const int slot = cc >> 3, half = cc & 7;
    const float* xp = x + xbase + (size_t)wid * 256 + cc;
#pragma unroll
    for (int it = 0; it < 8; ++it) {
      fvec4 v = *(const fvec4*)(xp + it * 8 * 256);
      int r = wid + it * 8;
      u16x4 u;
      u[0] = f2bf(v[0]); u[1] = f2bf(v[1]); u[2] = f2bf(v[2]); u[3] = f2bf(v[3]);
      *(u16x4*)&As[r * 256 + ((slot ^ (r & 7)) << 3) + half] = u;
    }
  }
  asm volatile("s_waitcnt lgkmcnt(0)" ::: "memory");
  __builtin_amdgcn_s_barrier();            // As visible — the ONLY barrier in this kernel

  f32x4 acc[3][4];
  const f32x4 z = {0.f, 0.f, 0.f, 0.f};
#pragma unroll
  for (int jt = 0; jt < 3; ++jt)
#pragma unroll
    for (int rt = 0; rt < 4; ++rt) acc[jt][rt] = z;

  const int bswz = (lr >> 1) & 3;          // B-read slot swizzle
#pragma unroll
  for (int ci = 0; ci < 8; ++ci) {
    const int buf = ci & 1;
    // counted wait: chunk ci is the 2nd-newest DMA group in FIFO -> vmcnt(3) retires it;
    // chunk ci+1 (newest, 3 ops) stays in flight. Last iter: full drain.
    if (ci == 7) asm volatile("s_waitcnt vmcnt(0)" ::: "memory");
    else         asm volatile("s_waitcnt vmcnt(3)" ::: "memory");
    __builtin_amdgcn_sched_barrier(0);
    // reads (LDS only)
    short8 a[4], b[3];
    const int kslot = ci * 4 + lk4;        // 0..31 within full 256-K row
#pragma unroll
    for (int rt = 0; rt < 4; ++rt) {
      int row = rt * 16 + lr;
      a[rt] = *(const short8*)&As[row * 256 + ((kslot ^ (row & 7)) << 3)];
    }
#pragma unroll
    for (int jt = 0; jt < 3; ++jt)
      b[jt] = *(const short8*)&Bs[buf * 12288 + wid * 1536 +
                                  (jt * 16 + lr) * 32 + ((lk4 ^ bswz) * 8)];
    // MFMAs: compiler-inserted precise lgkm waits; consuming a,b closes the WAR window
#pragma unroll
    for (int jt = 0; jt < 3; ++jt)
#pragma unroll
      for (int rt = 0; rt < 4; ++rt)
        acc[jt][rt] = mfma16(b[jt], a[rt], acc[jt][rt]);  // reg-dim = col
    __builtin_amdgcn_sched_barrier(0);     // DMA below stays AFTER the MFMA block
    if (ci < 6) {                          // issue chunk ci+2 into buf(ci&1)
      const u16* s = wsrc + (size_t)(ci + 2) * 12288;
      u16* d = bdst + buf * 12288;
#pragma unroll
      for (int j = 0; j < 3; ++j) gl16(s + j * 512, d + j * 512);
    }
    __builtin_amdgcn_sched_barrier(0);
  }

  // ---- epilogue: + bias, 8-chan-plane layout: store instr fills 2 planes x 256B ----
  const int rows0 = mt * 64;
#pragma unroll
  for (int jt = 0; jt < 3; ++jt) {
    int col0 = colbase + wid * 48 + jt * 16 + lk4 * 4;
    size_t pbase = (size_t)(col0 >> 3) * 524288 + (col0 & 7);
#pragma unroll
    for (int rt = 0; rt < 4; ++rt) {
      int row = rows0 + rt * 16 + lr;
      u16x4 u;
#pragma unroll
      for (int r = 0; r < 4; ++r) u[r] = f2bf(acc[jt][rt][r] + bb[jt][r]);
      *(u16x4*)&qkvB[pbase + (size_t)row * 8] = u;
    }
  }
}

// ---------------- merged attention ------------------------------------------------------
// blocks [0,8192): ws=8 n-half blocks; [8192,24576): ws=4. 1-wave blocks, 5952B LDS carve
// (ws=8 keeps only P in LDS; V gathered straight from global into regs). No barriers.
__global__ __launch_bounds__(64) void k_attn(const u16* __restrict__ qkvB,
                                             const float* __restrict__ bias8,
                                             const float* __restrict__ bias4,
                                             float* __restrict__ out) {
  __shared__ __align__(16) u16 sbuf[2976];   // 5952 B
  const int l = threadIdx.x;
  const int lr = l & 15, lk4 = l >> 4;
  const f32x4 z = {0.f, 0.f, 0.f, 0.f};
  const float scale = 0.17677669529663687f;  // 1/sqrt(32)

  if (blockIdx.x < 8192) {
    // ============ ws = 8, n-half blocks (group 1, channels 128..255) ============
    u16* plg = sbuf;                 // P [32 n][72 m] (2304 u16); reused as O f32 [32][33]
    const int lid = blockIdx.x;
    const int logical = (lid & 7) * 1024 + (lid >> 3);  // bijective: 8192 = 8*1024
    const int nh2 = logical & 1;             // n-half (fastest: halves share K/V in L2)
    const int g = (logical >> 1) & 3;
    const int wj = (logical >> 3) & 7, wi = (logical >> 6) & 7, Bg = logical >> 9;
    const int h0 = wi * 8, w0 = wj * 8;

    // ---- V^T fragments straight from global into regs (issued first; consumed in PV) ----
    short8 vbr[2][2];
#pragma unroll
    for (int kc = 0; kc < 2; ++kc)
#pragma unroll
      for (int te = 0; te < 2; ++te)
        vbr[kc][te] = gatherVT8(qkvB, 640 + g * 32 + te * 16 + lr,
                                Bg, h0, w0, kc * 32 + lk4 * 8);

    const int c8q = 16 + g * 4 + lk4;   // q chans 128+g*32+lk4*8
    const int c8k = 48 + g * 4 + lk4;   // k chans 384+g*32+lk4*8
    short8 aq[2], bk[4];
#pragma unroll
    for (int tn = 0; tn < 2; ++tn) {
      int n = nh2 * 32 + tn * 16 + lr;
      aq[tn] = ld8(qkvB, c8q, m_of(Bg, h0 + (n >> 3), w0 + (n & 7)));
    }
#pragma unroll
    for (int tm = 0; tm < 4; ++tm) {
      int m = tm * 16 + lr;
      bk[tm] = ld8(qkvB, c8k, m_of(Bg, h0 + (m >> 3), w0 + (m & 7)));
    }
    // S = q k^T  (8 MFMAs): rows n = nh2*32+tn*16+lk4*4+r, cols m = tm*16+lr
    f32x4 s[2][4];
#pragma unroll
    for (int tn = 0; tn < 2; ++tn)
#pragma unroll
      for (int tm = 0; tm < 4; ++tm) s[tn][tm] = mfma16(aq[tn], bk[tm], z);

#pragma unroll
    for (int tn = 0; tn < 2; ++tn)
#pragma unroll
      for (int tm = 0; tm < 4; ++tm)
#pragma unroll
        for (int r = 0; r < 4; ++r) {
          int n = nh2 * 32 + tn * 16 + lk4 * 4 + r, m = tm * 16 + lr;
          s[tn][tm][r] = s[tn][tm][r] * scale + bias8[(g * 64 + n) * 64 + m];
        }
    // softmax over m (row n lives in 16 lanes sharing l>>4)
    float invden[2][4];
#pragma unroll
    for (int tn = 0; tn < 2; ++tn)
#pragma unroll
      for (int r = 0; r < 4; ++r) {
        float mx = fmaxf(fmaxf(s[tn][0][r], s[tn][1][r]), fmaxf(s[tn][2][r], s[tn][3][r]));
#pragma unroll
        for (int d = 1; d < 16; d <<= 1) mx = fmaxf(mx, __shfl_xor(mx, d));
        float sum = 0.f;
#pragma unroll
        for (int tm = 0; tm < 4; ++tm) {
          float p = __expf(s[tn][tm][r] - mx);
          s[tn][tm][r] = p;
          sum += p;
        }
#pragma unroll
        for (int d = 1; d < 16; d <<= 1) sum += __shfl_xor(sum, d);
        invden[tn][r] = 1.f / sum;
      }
    // P -> LDS (bf16), local rows 0..31
#pragma unroll
    for (int tn = 0; tn < 2; ++tn)
#pragma unroll
      for (int tm = 0; tm < 4; ++tm)
#pragma unroll
        for (int r = 0; r < 4; ++r)
          plg[(tn * 16 + lk4 * 4 + r) * 72 + tm * 16 + lr] = f2bf(s[tn][tm][r]);
    wave_lds_fence();
    // O = P V  (8 MFMAs); V fragments already in regs
    f32x4 o[2][2];
#pragma unroll
    for (int tn = 0; tn < 2; ++tn) { o[tn][0] = z; o[tn][1] = z; }
#pragma unroll
    for (int kc = 0; kc < 2; ++kc) {
      short8 pa[2];
#pragma unroll
      for (int tn = 0; tn < 2; ++tn)
        pa[tn] = *(const short8*)&plg[(tn * 16 + lr) * 72 + kc * 32 + lk4 * 8];
#pragma unroll
      for (int tn = 0; tn < 2; ++tn)
#pragma unroll
        for (int te = 0; te < 2; ++te) o[tn][te] = mfma16(pa[tn], vbr[kc][te], o[tn][te]);
    }
    wave_lds_fence();
    // scale by 1/denom, transpose O through LDS (overlay on plg): [32][33] f32
    float* ol = (float*)plg;
#pragma unroll
    for (int tn = 0; tn < 2; ++tn)
#pragma unroll
      for (int te = 0; te < 2; ++te)
#pragma unroll
        for (int r = 0; r < 4; ++r) {
          int nloc = tn * 16 + lk4 * 4 + r;
          ol[nloc * 33 + te * 16 + lr] = o[tn][te][r] * invden[tn][r];
        }
    wave_lds_fence();
    // store: lane covers (token nloc = l&31) x (e-half = (l>>5)*16); 16 e's each
    {
      int nloc = l & 31, e0 = (l >> 5) * 16;
      int n = nh2 * 32 + nloc;
      int h = h0 + (n >> 3), w = w0 + (n & 7);
      size_t base = ((size_t)(Bg >> 2)) * 4194304 + (size_t)(((Bg & 3) * 2 + (h >> 5))) * 131072 +
                    (size_t)(((h >> 2) & 7)) * 16384 + (size_t)((h & 3) * 64 + w);
      const float* orow = ol + nloc * 33;
#pragma unroll
      for (int ee = 0; ee < 16; ++ee) {
        int c = 128 + g * 32 + e0 + ee;
        size_t idx = base + (size_t)(c >> 6) * 1048576 + (size_t)((c >> 3) & 7) * 2048 +
                     (size_t)(c & 7) * 256;
        out[idx] = orow[e0 + ee];
      }
    }
  } else {
    // ================= ws = 4 (group 0, channels 0..127) =================
    u16* vtw = sbuf;                       // V^T [e][m0..32] stride 40 (1280 u16)
    u16* plw = sbuf + 1280;                // P [n][m0..32] stride 40 (640 u16)
    float* olw = (float*)(sbuf + 1920);    // O [16][33] f32 (3840%4==0; 1920+1056 <= 2976)
    const int lid = blockIdx.x - 8192;
    const int logical = (lid & 7) * 2048 + (lid >> 3);  // bijective: 16384 = 8*2048
    const int g = logical & 3;
    const int wid2 = logical >> 2;         // window id in [0,4096)
    const int Bg = wid2 >> 8, wi = (wid2 >> 4) & 15, wj = wid2 & 15;
    const int h0 = wi * 4, w0 = wj * 4;
    const short8 z8 = {0, 0, 0, 0, 0, 0, 0, 0};

    // zero the K-padding (cols 16..31) of P and V^T
    {
      u16x4 z4 = {0, 0, 0, 0};
      *(u16x4*)&plw[(l & 15) * 40 + 16 + (l >> 4) * 4] = z4;
      *(short8*)&vtw[(l >> 1) * 40 + 16 + (l & 1) * 8] = z8;
    }
    const int mq = m_of(Bg, h0 + (lr >> 2), w0 + (lr & 3));

    short8 aq = ld8(qkvB, g * 4 + lk4, mq);          // q chans g*32+lk4*8
    short8 bk = ld8(qkvB, 32 + g * 4 + lk4, mq);     // k chans 256+g*32+lk4*8
    {
      short8 v = ld8(qkvB, 64 + g * 4 + lk4, mq);    // v chans 512+g*32+lk4*8
#pragma unroll
      for (int j = 0; j < 8; ++j) vtw[(lk4 * 8 + j) * 40 + lr] = (u16)v[j];
    }
    // S (1 MFMA), C rows n = lk4*4+r, cols m = lr
    f32x4 s = mfma16(aq, bk, z);
#pragma unroll
    for (int r = 0; r < 4; ++r) {
      int n = lk4 * 4 + r;
      s[r] = s[r] * scale + bias4[(g * 16 + n) * 16 + lr];
    }
    float invden[4];
#pragma unroll
    for (int r = 0; r < 4; ++r) {
      float mx = s[r];
#pragma unroll
      for (int d = 1; d < 16; d <<= 1) mx = fmaxf(mx, __shfl_xor(mx, d));
      float p = __expf(s[r] - mx);
      s[r] = p;
      float sum = p;
#pragma unroll
      for (int d = 1; d < 16; d <<= 1) sum += __shfl_xor(sum, d);
      invden[r] = 1.f / sum;
    }
    // P -> LDS
#pragma unroll
    for (int r = 0; r < 4; ++r) plw[(lk4 * 4 + r) * 40 + lr] = f2bf(s[r]);
    wave_lds_fence();
    // O = P V : 2 MFMAs (te halves), K zero-padded to 32
    f32x4 o[2];
#pragma unroll
    for (int te = 0; te < 2; ++te) {
      short8 pa = *(const short8*)&plw[lr * 40 + lk4 * 8];
      short8 vb = *(const short8*)&vtw[(te * 16 + lr) * 40 + lk4 * 8];
      o[te] = mfma16(pa, vb, z);
    }
#pragma unroll
    for (int te = 0; te < 2; ++te)
#pragma unroll
      for (int r = 0; r < 4; ++r) {
        int n = lk4 * 4 + r;
        olw[n * 33 + te * 16 + lr] = o[te][r] * invden[r];
      }
    wave_lds_fence();
    // store: lane = (token lr) x (e-chunk lk4)
    {
      int h = h0 + (lr >> 2), w = w0 + (lr & 3);
      size_t base = ((size_t)(Bg >> 2)) * 4194304 +
                    (size_t)(((Bg & 3) * 2 + (h >> 5))) * 131072 +
                    (size_t)(((h >> 2) & 7)) * 16384 + (size_t)((h & 3) * 64 + w);
#pragma unroll
      for (int ee = 0; ee < 8; ++ee) {
        int e = lk4 * 8 + ee;
        int c = g * 32 + e;
        size_t idx = base + (size_t)(c >> 6) * 1048576 + (size_t)((c >> 3) & 7) * 2048 +
                     (size_t)(c & 7) * 256;
        out[idx] = olw[lr * 33 + e];
      }
    }
  }
}

extern "C" void kernel_launch(void* const* d_in, const int* in_sizes, int n_in,
                              void* d_out, int out_size, void* d_ws, size_t ws_size,
                              hipStream_t stream) {
  const float* x = (const float*)d_in[0];
  const float* qkv_w = (const float*)d_in[1];
  const float* qkv_b = (const float*)d_in[2];
  const float* t0 = (const float*)d_in[3];
  const float* t1 = (const float*)d_in[4];
  float* out = (float*)d_out;
  char* ws = (char*)d_ws;

  u16* qkvB = (u16*)ws;                         // 96 planes * 524288 u16 = 100663296 B
  u16* wbp = (u16*)(ws + 100663296);            // 196608 u16       = 393216 B
  float* bias8 = (float*)(ws + 101056512);      // 4*64*64*4        = 65536 B
  float* bias4 = (float*)(ws + 101122048);      // 4*16*16*4        = 4096 B

  k_prep<<<256, 256, 0, stream>>>(qkv_w, t0, t1, wbp, bias4, bias8);
  k_gemm<<<2048, 512, 0, stream>>>(x, wbp, qkv_b, qkvB);
  k_attn<<<24576, 64, 0, stream>>>(qkvB, bias8, bias4, out);
}